// Round 15
// baseline (206.397 us; speedup 1.0000x reference)
//
#include <hip/hip_runtime.h>

// LSTM text classifier: emb-gather -> LSTM(512 steps) -> FC(32->2)
//   R15: halve fanout via v_fma_mix_f32. Seven engines measured busy 423-490 /
//   wall 620-650; the only still-reducible term is 32 readlanes (~128cyc).
//   h packed as f16x2 {h_2m, h_2m+1} (1 DPP + 1 cvt_pkrtz per step) -> ONE
//   readlane feeds TWO cells; v_fma_mix_f32 (full f32 rate, f32 acc, op_sel
//   picks f16 half from the SGPR pair) keeps weights+accum f32.
//   16 readlane + 64 mix-FMA vs 32+64. Accuracy: f16 h only (R12 precedent:
//   f16 h AND w gave absmax 1.95e-3, passed). DPP direction absorbed into
//   weight column order via R10's verified runtime probe.
//   Rest verbatim R6/R10: ptab ring, R8 tail (bcast_both+cs), waves_per_eu(1,1).

#define LOG2E 1.44269504088896340736f

typedef float f32x2 __attribute__((ext_vector_type(2)));
typedef unsigned uv2 __attribute__((ext_vector_type(2)));
typedef float f32x32 __attribute__((ext_vector_type(32)));
typedef __fp16 h16x2 __attribute__((ext_vector_type(2)));

__device__ __forceinline__ float fast_rcp(float x) { return __builtin_amdgcn_rcpf(x); }
__device__ __forceinline__ float fast_exp2(float x) { return __builtin_amdgcn_exp2f(x); }

// permlane32_swap(x,x): r.x = lo-half value in ALL lanes, r.y = hi-half value
// in ALL lanes. HW-verified (R8-R14, absmax 0.0).
__device__ __forceinline__ f32x2 bcast_both(float x) {
    uv2 r = __builtin_amdgcn_permlane32_swap(__float_as_uint(x), __float_as_uint(x),
                                             false, false);
    f32x2 o;
    o.x = __uint_as_float(r.x);
    o.y = __uint_as_float(r.y);
    return o;
}

// wave rotate-by-1 DPP (verified R10/R14, absmax 0 with runtime dir probe)
#define ROTA(V) __int_as_float(__builtin_amdgcn_mov_dpp(__float_as_int(V), 0x13C, 0xF, 0xF, true))

__device__ __forceinline__ unsigned pack2(float a, float b) {
#if __has_builtin(__builtin_amdgcn_cvt_pkrtz)
    return __builtin_bit_cast(unsigned, __builtin_amdgcn_cvt_pkrtz(a, b));
#else
    h16x2 r; r.x = (__fp16)a; r.y = (__fp16)b;
    return __builtin_bit_cast(unsigned, r);
#endif
}

// ---------------- K1: projected + prescaled embedding table ----------------
__global__ __launch_bounds__(64, 1) void build_ptab(
    const float4* __restrict__ emb4, const float4* __restrict__ wih4,
    const float* __restrict__ bih, const float* __restrict__ bhh,
    float2* __restrict__ ptab, int nrows) {
    const int lane = threadIdx.x;

    float w0[32], w1[32];
#pragma unroll
    for (int q = 0; q < 8; ++q) {
        float4 a = wih4[lane * 8 + q];
        float4 b = wih4[(lane + 64) * 8 + q];
        w0[4 * q + 0] = a.x; w0[4 * q + 1] = a.y; w0[4 * q + 2] = a.z; w0[4 * q + 3] = a.w;
        w1[4 * q + 0] = b.x; w1[4 * q + 1] = b.y; w1[4 * q + 2] = b.z; w1[4 * q + 3] = b.w;
    }
    const float bias0 = bih[lane] + bhh[lane];
    const float bias1 = bih[lane + 64] + bhh[lane + 64];
    const float s0 = -LOG2E;                                   // rows l: i,f -> sigmoid
    const float s1 = (lane < 32) ? (2.0f * LOG2E) : (-LOG2E);  // rows l+64: g tanh / o sigmoid

    for (int v = blockIdx.x; v < nrows; v += gridDim.x) {
        float a0 = bias0, a1 = bias1;
#pragma unroll
        for (int q = 0; q < 8; ++q) {
            float4 e = emb4[v * 8 + q];  // wave-uniform -> cache broadcast
            a0 = fmaf(e.x, w0[4 * q + 0], a0);
            a0 = fmaf(e.y, w0[4 * q + 1], a0);
            a0 = fmaf(e.z, w0[4 * q + 2], a0);
            a0 = fmaf(e.w, w0[4 * q + 3], a0);
            a1 = fmaf(e.x, w1[4 * q + 0], a1);
            a1 = fmaf(e.y, w1[4 * q + 1], a1);
            a1 = fmaf(e.z, w1[4 * q + 2], a1);
            a1 = fmaf(e.w, w1[4 * q + 3], a1);
        }
        ptab[v * 64 + lane] = make_float2(a0 * s0, a1 * s1);  // coalesced 512B/row
    }
}

// mix-FMA: ACC(f32) += W(f32) * f16-half of SGPR pair HP (SEL=0 lo, 1 hi)
#define MIXFMA(ACC, W, HP, SEL)                                                \
    asm("v_fma_mix_f32 %0, %1, %2, %0 op_sel:[0," #SEL ",0] op_sel_hi:[0,1,0]" \
        : "+v"(ACC)                                                            \
        : "v"(W), "s"(HP));

// one k-pair: 1 readlane (even lane 2M holds pair {h_2M, h_partner}),
// 4 mix-FMAs. Weight interleave: wf*[2M] pairs lo half, wf*[2M+1] hi half.
#define KPAIR(M, XA, YA)                                                       \
    {                                                                          \
        unsigned _hp = (unsigned)__builtin_amdgcn_readlane((int)hp, 2 * (M));  \
        MIXFMA(XA, wf0[2 * (M)], _hp, 0)                                       \
        MIXFMA(XA, wf0[2 * (M) + 1], _hp, 1)                                   \
        MIXFMA(YA, wf1[2 * (M)], _hp, 0)                                       \
        MIXFMA(YA, wf1[2 * (M) + 1], _hp, 1)                                   \
    }

// one LSTM step; P = packed {g0,g1} prescaled pre-activations.
// Kernel scope: h, cs, hp, wf0, wf1. h,cs valid in ALL 64 lanes (periodic-32);
// cs = c * 2*log2e; hp = f16x2 {h_lane, h_rotA(lane)}.
#define STEP(P)                                                                \
    do {                                                                       \
        float _x0 = (P).x, _x1 = 0.f, _x2 = 0.f, _x3 = 0.f;                    \
        float _y0 = (P).y, _y1 = 0.f, _y2 = 0.f, _y3 = 0.f;                    \
        KPAIR(0, _x0, _y0) KPAIR(1, _x1, _y1)                                  \
        KPAIR(2, _x2, _y2) KPAIR(3, _x3, _y3)                                  \
        KPAIR(4, _x0, _y0) KPAIR(5, _x1, _y1)                                  \
        KPAIR(6, _x2, _y2) KPAIR(7, _x3, _y3)                                  \
        KPAIR(8, _x0, _y0) KPAIR(9, _x1, _y1)                                  \
        KPAIR(10, _x2, _y2) KPAIR(11, _x3, _y3)                                \
        KPAIR(12, _x0, _y0) KPAIR(13, _x1, _y1)                                \
        KPAIR(14, _x2, _y2) KPAIR(15, _x3, _y3)                                \
        float _A0 = (_x0 + _x1) + (_x2 + _x3); /* lo: y_i*s0, hi: y_f*s0 */    \
        float _A1 = (_y0 + _y1) + (_y2 + _y3); /* lo: y_g*s1, hi: y_o*s1 */    \
        float _sg = fast_rcp(1.0f + fast_exp2(_A0)); /* lo:i  hi:f */          \
        float _r1 = fast_rcp(1.0f + fast_exp2(_A1)); /* lo:gf hi:o */          \
        f32x2 _bs = bcast_both(_sg); /* .x=i .y=f (all lanes) */               \
        f32x2 _br = bcast_both(_r1); /* .x=gf .y=o (all lanes) */              \
        float _ggs = fmaf(-4.0f * LOG2E, _br.x, 2.0f * LOG2E); /* tanh(g)*2log2e */ \
        cs = fmaf(_bs.y, cs, _bs.x * _ggs);                                    \
        h = _br.y * fmaf(-2.0f, fast_rcp(1.0f + fast_exp2(cs)), 1.0f);         \
        hp = pack2(h, ROTA(h));                                                \
    } while (0)

// ---------------- K2: LSTM scan, one wave per batch element ----------------
template <bool PTAB>
__global__ __launch_bounds__(64)
__attribute__((amdgpu_waves_per_eu(1, 1)))  // pressure target = 1 wave/EU (R6, verified)
void lstm_scan(
    const int* __restrict__ x,
    const float2* __restrict__ ptab,
    const float* __restrict__ emb,
    const float* __restrict__ wih,
    const float* __restrict__ bih,
    const float* __restrict__ bhh,
    const float* __restrict__ whh,
    const float* __restrict__ fcw,
    const float* __restrict__ fcb,
    float* __restrict__ out,
    int S) {
    extern __shared__ int xrow[];
    const int b = blockIdx.x;
    const int lane = threadIdx.x;

    // token ids in LDS, padded so the prefetch ring never reads OOB
    for (int i = lane; i < S + 16; i += 64) xrow[i] = (i < S) ? x[(size_t)b * S + i] : 0;
    __syncthreads();

    const float s0 = -LOG2E;
    const float s1 = (lane < 32) ? (2.0f * LOG2E) : (-LOG2E);

    // probe ROTA receive direction (verified R10): hp's hi half at lane 2m is
    // h_{(2m+dA)&31}; weight hi-column follows dA.
    int dA;
    {
        int g = __builtin_amdgcn_mov_dpp(lane, 0x13C, 0xF, 0xF, true);
        dA = (g == ((lane + 1) & 63)) ? 1 : -1;
    }

    // recurrent weights, prescaled, pair-interleaved to match hp halves:
    //   wf[2m]   -> column 2m          (hp lo half)
    //   wf[2m+1] -> column (2m+dA)&31  (hp hi half)
    f32x32 wf0, wf1;
    {
        const int r0w = lane * 32;
        const int r1w = (lane + 64) * 32;
#pragma unroll
        for (int m = 0; m < 16; ++m) {
            int c0 = 2 * m;
            int c1 = (2 * m + dA) & 31;
            wf0[2 * m + 0] = whh[r0w + c0] * s0;
            wf0[2 * m + 1] = whh[r0w + c1] * s0;
            wf1[2 * m + 0] = whh[r1w + c0] * s1;
            wf1[2 * m + 1] = whh[r1w + c1] * s1;
        }
    }

    float h = 0.0f, cs = 0.0f;  // valid in all 64 lanes (periodic-32); cs = c*2log2e
    unsigned hp = 0;            // f16x2 {h_lane, h_rotA} = {0,0}

    if constexpr (PTAB) {
        const char* pb = (const char*)ptab + (unsigned)(lane << 3);
        int i0 = xrow[4], i1 = xrow[5], i2 = xrow[6], i3 = xrow[7];
        f32x2 p0 = *(const f32x2*)(pb + ((unsigned)xrow[0] << 9));
        f32x2 p1 = *(const f32x2*)(pb + ((unsigned)xrow[1] << 9));
        f32x2 p2 = *(const f32x2*)(pb + ((unsigned)xrow[2] << 9));
        f32x2 p3 = *(const f32x2*)(pb + ((unsigned)xrow[3] << 9));
        int t = 0;
        for (; t + 8 <= S; t += 4) {
            STEP(p0); p0 = *(const f32x2*)(pb + ((unsigned)i0 << 9)); i0 = xrow[t + 8];
            STEP(p1); p1 = *(const f32x2*)(pb + ((unsigned)i1 << 9)); i1 = xrow[t + 9];
            STEP(p2); p2 = *(const f32x2*)(pb + ((unsigned)i2 << 9)); i2 = xrow[t + 10];
            STEP(p3); p3 = *(const f32x2*)(pb + ((unsigned)i3 << 9)); i3 = xrow[t + 11];
        }
        if (t + 0 < S) STEP(p0);
        if (t + 1 < S) STEP(p1);
        if (t + 2 < S) STEP(p2);
        if (t + 3 < S) STEP(p3);
        if (t + 4 < S) { f32x2 q = *(const f32x2*)(pb + ((unsigned)i0 << 9)); STEP(q); }
        if (t + 5 < S) { f32x2 q = *(const f32x2*)(pb + ((unsigned)i1 << 9)); STEP(q); }
        if (t + 6 < S) { f32x2 q = *(const f32x2*)(pb + ((unsigned)i2 << 9)); STEP(q); }
    } else {
        // fallback: on-the-fly input projection (workspace too small); cold path
        f32x32 wi0, wi1;
        {
            const float4* wih4 = (const float4*)wih;
#pragma unroll
            for (int q = 0; q < 8; ++q) {
                float4 a = wih4[lane * 8 + q];
                float4 bb = wih4[(lane + 64) * 8 + q];
                wi0[4 * q + 0] = a.x * s0; wi0[4 * q + 1] = a.y * s0;
                wi0[4 * q + 2] = a.z * s0; wi0[4 * q + 3] = a.w * s0;
                wi1[4 * q + 0] = bb.x * s1; wi1[4 * q + 1] = bb.y * s1;
                wi1[4 * q + 2] = bb.z * s1; wi1[4 * q + 3] = bb.w * s1;
            }
        }
        const float bias0 = (bih[lane] + bhh[lane]) * s0;
        const float bias1 = (bih[lane + 64] + bhh[lane + 64]) * s1;
        const float4* emb4 = (const float4*)emb;
        for (int t = 0; t < S; ++t) {
            int idx = xrow[t];
            float a0 = bias0, a1 = bias1;
#pragma unroll
            for (int q = 0; q < 8; ++q) {
                float4 e = emb4[(size_t)idx * 8 + q];
                a0 = fmaf(e.x, wi0[4 * q + 0], a0);
                a0 = fmaf(e.y, wi0[4 * q + 1], a0);
                a0 = fmaf(e.z, wi0[4 * q + 2], a0);
                a0 = fmaf(e.w, wi0[4 * q + 3], a0);
                a1 = fmaf(e.x, wi1[4 * q + 0], a1);
                a1 = fmaf(e.y, wi1[4 * q + 1], a1);
                a1 = fmaf(e.z, wi1[4 * q + 2], a1);
                a1 = fmaf(e.w, wi1[4 * q + 3], a1);
            }
            f32x2 _p; _p.x = a0; _p.y = a1;
            STEP(_p);
        }
    }

    // FC: out[b][n] = sum_k h_k * fc_w[n][k] + fc_b[n]; h periodic-32 ->
    // mask to lanes 0..31 to avoid double counting
    float wv0 = fcw[lane & 31];
    float wv1 = fcw[32 + (lane & 31)];
    float p0v = (lane < 32) ? h * wv0 : 0.0f;
    float p1v = (lane < 32) ? h * wv1 : 0.0f;
#pragma unroll
    for (int m = 32; m >= 1; m >>= 1) {
        p0v += __shfl_xor(p0v, m, 64);
        p1v += __shfl_xor(p1v, m, 64);
    }
    if (lane == 0) {
        out[b * 2 + 0] = p0v + fcb[0];
        out[b * 2 + 1] = p1v + fcb[1];
    }
}

extern "C" void kernel_launch(void* const* d_in, const int* in_sizes, int n_in,
                              void* d_out, int out_size, void* d_ws, size_t ws_size,
                              hipStream_t stream) {
    const int* x = (const int*)d_in[0];
    const float* emb = (const float*)d_in[1];
    const float* wih = (const float*)d_in[2];
    const float* whh = (const float*)d_in[3];
    const float* bih = (const float*)d_in[4];
    const float* bhh = (const float*)d_in[5];
    const float* fcw = (const float*)d_in[6];
    const float* fcb = (const float*)d_in[7];
    float* out = (float*)d_out;

    const int B = out_size / 2;          // 1024
    const int S = in_sizes[0] / B;       // 512
    const int nrows = in_sizes[1] / 32;  // 50001 (EMB=32)

    const size_t need = (size_t)nrows * 64 * sizeof(float2);  // 25.6 MB
    const size_t smem = (size_t)(S + 16) * sizeof(int);

    if (ws_size >= need) {
        float2* ptab = (float2*)d_ws;
        int nb = nrows < 8192 ? nrows : 8192;
        build_ptab<<<nb, 64, 0, stream>>>((const float4*)emb, (const float4*)wih,
                                          bih, bhh, ptab, nrows);
        lstm_scan<true><<<B, 64, smem, stream>>>(x, ptab, emb, wih, bih, bhh, whh,
                                                 fcw, fcb, out, S);
    } else {
        lstm_scan<false><<<B, 64, smem, stream>>>(x, nullptr, emb, wih, bih, bhh, whh,
                                                  fcw, fcb, out, S);
    }
}

// Round 16
// 138.152 us; speedup vs baseline: 1.4940x; 1.4940x over previous
//
#include <hip/hip_runtime.h>

// LSTM text classifier: emb-gather -> LSTM(512 steps) -> FC(32->2)
//   FINAL (= R10, best of 8 measured engines; see ledger in session notes).
//   K1 build_ptab: ptab[v] = (emb[v] @ w_ih^T + b_ih + b_hh) * gate_scale
//      (folds log2e so the scan uses raw v_exp_f32; 25.6MB in d_ws, L3-resident)
//   K2 lstm_scan: 1 wave per batch element (1024 waves = 1/SIMD, occupancy
//      is launch-limited); amdgpu_waves_per_eu(1,1) so the allocator targets
//      512 VGPRs and keeps w_hh register-resident (R6 fix, verified VGPR 132).
//   Dot engine: identity + dual-direction wave-DPP rotate chains (ROR+ROL,
//      runtime direction-probed), 31 full-rate v_mov_dpp + 64 v_fma_f32.
//   Tail: h,cs valid in all 64 lanes via permlane32_swap dual-broadcast;
//      cs = c*2log2e kills a dependent mul; 4 trans ops/step total.
//   Measured: 423 busy / 622 wall cyc/step; structural floor at 1 wave/SIMD
//   (512 serial steps; packed math is half-rate; all fanout ops ~4cyc).

#define LOG2E 1.44269504088896340736f

typedef float f32x2 __attribute__((ext_vector_type(2)));
typedef unsigned uv2 __attribute__((ext_vector_type(2)));
typedef float f32x16 __attribute__((ext_vector_type(16)));
typedef float f32x32 __attribute__((ext_vector_type(32)));

__device__ __forceinline__ float fast_rcp(float x) { return __builtin_amdgcn_rcpf(x); }
__device__ __forceinline__ float fast_exp2(float x) { return __builtin_amdgcn_exp2f(x); }

// permlane32_swap(x,x): r.x = lo-half value in ALL lanes, r.y = hi-half value
// in ALL lanes. HW-verified (R8-R14, absmax 0.0).
__device__ __forceinline__ f32x2 bcast_both(float x) {
    uv2 r = __builtin_amdgcn_permlane32_swap(__float_as_uint(x), __float_as_uint(x),
                                             false, false);
    f32x2 o;
    o.x = __uint_as_float(r.x);  // lo value, all lanes
    o.y = __uint_as_float(r.y);  // hi value, all lanes
    return o;
}

// wave-level rotate-by-1 DPP (full-rate VALU). 0x13C = WAVE_ROR:1,
// 0x134 = WAVE_ROL:1. Directions are runtime-probed.
#define ROTA(V) __int_as_float(__builtin_amdgcn_mov_dpp(__float_as_int(V), 0x13C, 0xF, 0xF, true))
#define ROTB(V) __int_as_float(__builtin_amdgcn_mov_dpp(__float_as_int(V), 0x134, 0xF, 0xF, true))

// ---------------- K1: projected + prescaled embedding table ----------------
__global__ __launch_bounds__(64, 1) void build_ptab(
    const float4* __restrict__ emb4, const float4* __restrict__ wih4,
    const float* __restrict__ bih, const float* __restrict__ bhh,
    float2* __restrict__ ptab, int nrows) {
    const int lane = threadIdx.x;

    float w0[32], w1[32];
#pragma unroll
    for (int q = 0; q < 8; ++q) {
        float4 a = wih4[lane * 8 + q];
        float4 b = wih4[(lane + 64) * 8 + q];
        w0[4 * q + 0] = a.x; w0[4 * q + 1] = a.y; w0[4 * q + 2] = a.z; w0[4 * q + 3] = a.w;
        w1[4 * q + 0] = b.x; w1[4 * q + 1] = b.y; w1[4 * q + 2] = b.z; w1[4 * q + 3] = b.w;
    }
    const float bias0 = bih[lane] + bhh[lane];
    const float bias1 = bih[lane + 64] + bhh[lane + 64];
    const float s0 = -LOG2E;                                   // rows l: i,f -> sigmoid
    const float s1 = (lane < 32) ? (2.0f * LOG2E) : (-LOG2E);  // rows l+64: g tanh / o sigmoid

    for (int v = blockIdx.x; v < nrows; v += gridDim.x) {
        float a0 = bias0, a1 = bias1;
#pragma unroll
        for (int q = 0; q < 8; ++q) {
            float4 e = emb4[v * 8 + q];  // wave-uniform -> cache broadcast
            a0 = fmaf(e.x, w0[4 * q + 0], a0);
            a0 = fmaf(e.y, w0[4 * q + 1], a0);
            a0 = fmaf(e.z, w0[4 * q + 2], a0);
            a0 = fmaf(e.w, w0[4 * q + 3], a0);
            a1 = fmaf(e.x, w1[4 * q + 0], a1);
            a1 = fmaf(e.y, w1[4 * q + 1], a1);
            a1 = fmaf(e.z, w1[4 * q + 2], a1);
            a1 = fmaf(e.w, w1[4 * q + 3], a1);
        }
        ptab[v * 64 + lane] = make_float2(a0 * s0, a1 * s1);  // coalesced 512B/row
    }
}

// one LSTM step; P = packed {g0,g1} prescaled pre-activations.
// Uses kernel-scope h, cs, wI0, wI1, wA0, wA1, wB0, wB1.
// h, cs valid in ALL 64 lanes (periodic-32); cs = c * 2*log2e.
// Dot: identity slot + chain A (16 RORs) + chain B (15 ROLs) = 32 columns.
#define STEP(P)                                                                \
    do {                                                                       \
        float _a0 = fmaf(h, wI0, (P).x);                                       \
        float _b0 = fmaf(h, wI1, (P).y);                                       \
        float _a1 = 0.0f, _b1 = 0.0f;                                          \
        float _hA = h, _hB = h;                                                \
        _Pragma("unroll") for (int _j = 0; _j < 15; ++_j) {                    \
            _hA = ROTA(_hA);                                                   \
            _a0 = fmaf(_hA, wA0[_j], _a0);                                     \
            _b0 = fmaf(_hA, wA1[_j], _b0);                                     \
            _hB = ROTB(_hB);                                                   \
            _a1 = fmaf(_hB, wB0[_j], _a1);                                     \
            _b1 = fmaf(_hB, wB1[_j], _b1);                                     \
        }                                                                      \
        _hA = ROTA(_hA);                                                       \
        _a0 = fmaf(_hA, wA0[15], _a0);                                         \
        _b0 = fmaf(_hA, wA1[15], _b0);                                         \
        float _A0 = _a0 + _a1; /* lo: y_i*s0, hi: y_f*s0 */                    \
        float _A1 = _b0 + _b1; /* lo: y_g*s1, hi: y_o*s1 */                    \
        float _sg = fast_rcp(1.0f + fast_exp2(_A0)); /* lo:i  hi:f */          \
        float _r1 = fast_rcp(1.0f + fast_exp2(_A1)); /* lo:gf hi:o */          \
        f32x2 _bs = bcast_both(_sg); /* .x=i .y=f (all lanes) */               \
        f32x2 _br = bcast_both(_r1); /* .x=gf .y=o (all lanes) */              \
        float _ggs = fmaf(-4.0f * LOG2E, _br.x, 2.0f * LOG2E); /* tanh(g)*2log2e */ \
        cs = fmaf(_bs.y, cs, _bs.x * _ggs);                                    \
        h = _br.y * fmaf(-2.0f, fast_rcp(1.0f + fast_exp2(cs)), 1.0f);         \
    } while (0)

// ---------------- K2: LSTM scan, one wave per batch element ----------------
template <bool PTAB>
__global__ __launch_bounds__(64)
__attribute__((amdgpu_waves_per_eu(1, 1)))  // pressure target = 1 wave/EU (R6, verified)
void lstm_scan(
    const int* __restrict__ x,
    const float2* __restrict__ ptab,
    const float* __restrict__ emb,
    const float* __restrict__ wih,
    const float* __restrict__ bih,
    const float* __restrict__ bhh,
    const float* __restrict__ whh,
    const float* __restrict__ fcw,
    const float* __restrict__ fcb,
    float* __restrict__ out,
    int S) {
    extern __shared__ int xrow[];
    const int b = blockIdx.x;
    const int lane = threadIdx.x;

    // token ids in LDS, padded so the prefetch ring never reads OOB
    for (int i = lane; i < S + 16; i += 64) xrow[i] = (i < S) ? x[(size_t)b * S + i] : 0;
    __syncthreads();

    const float s0 = -LOG2E;
    const float s1 = (lane < 32) ? (2.0f * LOG2E) : (-LOG2E);

    // probe both wave-rotate directions (wave-uniform); a convention mismatch
    // flips col sign instead of corrupting silently
    int dirA, dirB;
    {
        int gA = __builtin_amdgcn_mov_dpp(lane, 0x13C, 0xF, 0xF, true);
        dirA = (gA == ((lane + 1) & 63)) ? 1 : -1;
        int gB = __builtin_amdgcn_mov_dpp(lane, 0x134, 0xF, 0xF, true);
        dirB = (gB == ((lane + 63) & 63)) ? -1 : 1;
    }

    // recurrent weights, systolic layout, prescaled:
    //   identity slot: col = lane&31
    //   chain A slot j: col = (lane + dirA*(j+1)) & 31, j = 0..15
    //   chain B slot j: col = (lane + dirB*(j+1)) & 31, j = 0..14
    float wI0, wI1;
    f32x16 wA0, wA1, wB0, wB1;
    {
        const int r0 = lane * 32;
        const int r1 = (lane + 64) * 32;
        wI0 = whh[r0 + (lane & 31)] * s0;
        wI1 = whh[r1 + (lane & 31)] * s1;
#pragma unroll
        for (int j = 0; j < 16; ++j) {
            int cA = (lane + dirA * (j + 1)) & 31;
            wA0[j] = whh[r0 + cA] * s0;
            wA1[j] = whh[r1 + cA] * s1;
        }
#pragma unroll
        for (int j = 0; j < 15; ++j) {
            int cB = (lane + dirB * (j + 1)) & 31;
            wB0[j] = whh[r0 + cB] * s0;
            wB1[j] = whh[r1 + cB] * s1;
        }
        wB0[15] = 0.0f;
        wB1[15] = 0.0f;
    }

    float h = 0.0f, cs = 0.0f;  // valid in all 64 lanes (periodic-32); cs = c*2log2e

    if constexpr (PTAB) {
        // 32-bit offset addressing: ptab is 25.6MB, idx<<9 fits unsigned
        const char* pb = (const char*)ptab + (unsigned)(lane << 3);
        // p ring = pre-activations for steps t..t+3; i ring = tokens t+4..t+7
        int i0 = xrow[4], i1 = xrow[5], i2 = xrow[6], i3 = xrow[7];
        f32x2 p0 = *(const f32x2*)(pb + ((unsigned)xrow[0] << 9));
        f32x2 p1 = *(const f32x2*)(pb + ((unsigned)xrow[1] << 9));
        f32x2 p2 = *(const f32x2*)(pb + ((unsigned)xrow[2] << 9));
        f32x2 p3 = *(const f32x2*)(pb + ((unsigned)xrow[3] << 9));
        int t = 0;
        for (; t + 8 <= S; t += 4) {
            STEP(p0); p0 = *(const f32x2*)(pb + ((unsigned)i0 << 9)); i0 = xrow[t + 8];
            STEP(p1); p1 = *(const f32x2*)(pb + ((unsigned)i1 << 9)); i1 = xrow[t + 9];
            STEP(p2); p2 = *(const f32x2*)(pb + ((unsigned)i2 << 9)); i2 = xrow[t + 10];
            STEP(p3); p3 = *(const f32x2*)(pb + ((unsigned)i3 << 9)); i3 = xrow[t + 11];
        }
        if (t + 0 < S) STEP(p0);
        if (t + 1 < S) STEP(p1);
        if (t + 2 < S) STEP(p2);
        if (t + 3 < S) STEP(p3);
        if (t + 4 < S) { f32x2 q = *(const f32x2*)(pb + ((unsigned)i0 << 9)); STEP(q); }
        if (t + 5 < S) { f32x2 q = *(const f32x2*)(pb + ((unsigned)i1 << 9)); STEP(q); }
        if (t + 6 < S) { f32x2 q = *(const f32x2*)(pb + ((unsigned)i2 << 9)); STEP(q); }
    } else {
        // fallback: on-the-fly input projection (workspace too small); cold path
        f32x32 wi0, wi1;
        {
            const float4* wih4 = (const float4*)wih;
#pragma unroll
            for (int q = 0; q < 8; ++q) {
                float4 a = wih4[lane * 8 + q];
                float4 bb = wih4[(lane + 64) * 8 + q];
                wi0[4 * q + 0] = a.x * s0; wi0[4 * q + 1] = a.y * s0;
                wi0[4 * q + 2] = a.z * s0; wi0[4 * q + 3] = a.w * s0;
                wi1[4 * q + 0] = bb.x * s1; wi1[4 * q + 1] = bb.y * s1;
                wi1[4 * q + 2] = bb.z * s1; wi1[4 * q + 3] = bb.w * s1;
            }
        }
        const float bias0 = (bih[lane] + bhh[lane]) * s0;
        const float bias1 = (bih[lane + 64] + bhh[lane + 64]) * s1;
        const float4* emb4 = (const float4*)emb;
        for (int t = 0; t < S; ++t) {
            int idx = xrow[t];
            float a0 = bias0, a1 = bias1;
#pragma unroll
            for (int q = 0; q < 8; ++q) {
                float4 e = emb4[(size_t)idx * 8 + q];
                a0 = fmaf(e.x, wi0[4 * q + 0], a0);
                a0 = fmaf(e.y, wi0[4 * q + 1], a0);
                a0 = fmaf(e.z, wi0[4 * q + 2], a0);
                a0 = fmaf(e.w, wi0[4 * q + 3], a0);
                a1 = fmaf(e.x, wi1[4 * q + 0], a1);
                a1 = fmaf(e.y, wi1[4 * q + 1], a1);
                a1 = fmaf(e.z, wi1[4 * q + 2], a1);
                a1 = fmaf(e.w, wi1[4 * q + 3], a1);
            }
            f32x2 _p; _p.x = a0; _p.y = a1;
            STEP(_p);
        }
    }

    // FC: out[b][n] = sum_k h_k * fc_w[n][k] + fc_b[n]; h periodic-32 ->
    // mask to lanes 0..31 to avoid double counting
    float wv0 = fcw[lane & 31];
    float wv1 = fcw[32 + (lane & 31)];
    float p0v = (lane < 32) ? h * wv0 : 0.0f;
    float p1v = (lane < 32) ? h * wv1 : 0.0f;
#pragma unroll
    for (int m = 32; m >= 1; m >>= 1) {
        p0v += __shfl_xor(p0v, m, 64);
        p1v += __shfl_xor(p1v, m, 64);
    }
    if (lane == 0) {
        out[b * 2 + 0] = p0v + fcb[0];
        out[b * 2 + 1] = p1v + fcb[1];
    }
}

extern "C" void kernel_launch(void* const* d_in, const int* in_sizes, int n_in,
                              void* d_out, int out_size, void* d_ws, size_t ws_size,
                              hipStream_t stream) {
    const int* x = (const int*)d_in[0];
    const float* emb = (const float*)d_in[1];
    const float* wih = (const float*)d_in[2];
    const float* whh = (const float*)d_in[3];
    const float* bih = (const float*)d_in[4];
    const float* bhh = (const float*)d_in[5];
    const float* fcw = (const float*)d_in[6];
    const float* fcb = (const float*)d_in[7];
    float* out = (float*)d_out;

    const int B = out_size / 2;          // 1024
    const int S = in_sizes[0] / B;       // 512
    const int nrows = in_sizes[1] / 32;  // 50001 (EMB=32)

    const size_t need = (size_t)nrows * 64 * sizeof(float2);  // 25.6 MB
    const size_t smem = (size_t)(S + 16) * sizeof(int);

    if (ws_size >= need) {
        float2* ptab = (float2*)d_ws;
        int nb = nrows < 8192 ? nrows : 8192;
        build_ptab<<<nb, 64, 0, stream>>>((const float4*)emb, (const float4*)wih,
                                          bih, bhh, ptab, nrows);
        lstm_scan<true><<<B, 64, smem, stream>>>(x, ptab, emb, wih, bih, bhh, whh,
                                                 fcw, fcb, out, S);
    } else {
        lstm_scan<false><<<B, 64, smem, stream>>>(x, nullptr, emb, wih, bih, bhh, whh,
                                                  fcw, fcb, out, S);
    }
}